// Round 16
// baseline (1025.760 us; speedup 1.0000x reference)
//
#include <hip/hip_runtime.h>
#include <hip/hip_bf16.h>

#define S_LEN 256
#define NB 32
#define UDIM 512
#define WGS 32    // workgroups per chain

typedef __attribute__((ext_vector_type(8))) short bf16x8;
typedef __attribute__((ext_vector_type(4))) float f32x4;
typedef __attribute__((ext_vector_type(4))) unsigned u32x4;

struct WPtrs { const float* p[8]; };
struct BPtrs { const float* p[4]; };

// hist layout: [c][slot][unit][b][j]  -- each unit owns a CONTIGUOUS 1KB slab
#define SLAB(c, slot) ((((size_t)(c) * 257 + (slot)) * 32) << 10)

__device__ __forceinline__ unsigned short f2bf(float f) {
  union { float f; unsigned u; } v; v.f = f;
  unsigned r = v.u + 0x7fffu + ((v.u >> 16) & 1u);
  return (unsigned short)(r >> 16);
}

// ---- coherent (cross-XCD) memory ops ----
__device__ __forceinline__ void st_u32c(void* p, unsigned v) {
  asm volatile("global_store_dword %0, %1, off sc0 sc1" :: "v"(p), "v"(v) : "memory");
}

// Depth-3 pipelined hint poll: 3 coherent 4B loads stay in flight; each
// iteration checks the oldest (vmcnt(2) = wait until <=2 outstanding),
// re-issues it, rotates. Poll period ~ RT/3 instead of RT. Exits (all lanes
// non-sentinel on one sample) drain vmcnt(0). Lanes with self-produced slabs
// are pointed at a never-sentinel dummy address by the caller.
__device__ __forceinline__ void poll3(const char* hp) {
  unsigned h0, h1, h2;
  asm volatile(
    "global_load_dword %0, %3, off sc0 sc1\n\t"
    "global_load_dword %1, %3, off sc0 sc1\n\t"
    "global_load_dword %2, %3, off sc0 sc1\n\t"
    "Lp%=:\n\t"
    "s_waitcnt vmcnt(2)\n\t"
    "v_cmp_eq_u32 vcc, -1, %0\n\t"
    "s_cbranch_vccz Ld%=\n\t"
    "global_load_dword %0, %3, off sc0 sc1\n\t"
    "s_waitcnt vmcnt(2)\n\t"
    "v_cmp_eq_u32 vcc, -1, %1\n\t"
    "s_cbranch_vccz Ld%=\n\t"
    "global_load_dword %1, %3, off sc0 sc1\n\t"
    "s_waitcnt vmcnt(2)\n\t"
    "v_cmp_eq_u32 vcc, -1, %2\n\t"
    "s_cbranch_vccz Ld%=\n\t"
    "global_load_dword %2, %3, off sc0 sc1\n\t"
    "s_branch Lp%=\n\t"
    "Ld%=:\n\t"
    "s_waitcnt vmcnt(0)"
    : "=&v"(h0), "=&v"(h1), "=&v"(h2)
    : "v"(hp)
    : "vcc", "memory");
}

// Blocking coherent 16-load over the unit-slab layout; vmcnt(0) INSIDE the
// asm; returns per-lane "no 0xFFFFFFFF sentinel word" (commit validation).
__device__ __forceinline__ bool ld_slab16(const char* b0, const char* b1,
                                          const char* b2, const char* b3,
                                          bf16x8* afr0, bf16x8* afr1) {
  u32x4 q0,q1,q2,q3,q4,q5,q6,q7,q8,q9,q10,q11,q12,q13,q14,q15;
  asm volatile(
    "global_load_dwordx4 %0, %16, off sc0 sc1\n\t"
    "global_load_dwordx4 %1, %16, off offset:512 sc0 sc1\n\t"
    "global_load_dwordx4 %2, %16, off offset:2048 sc0 sc1\n\t"
    "global_load_dwordx4 %3, %16, off offset:2560 sc0 sc1\n\t"
    "global_load_dwordx4 %4, %17, off sc0 sc1\n\t"
    "global_load_dwordx4 %5, %17, off offset:512 sc0 sc1\n\t"
    "global_load_dwordx4 %6, %17, off offset:2048 sc0 sc1\n\t"
    "global_load_dwordx4 %7, %17, off offset:2560 sc0 sc1\n\t"
    "global_load_dwordx4 %8, %18, off sc0 sc1\n\t"
    "global_load_dwordx4 %9, %18, off offset:512 sc0 sc1\n\t"
    "global_load_dwordx4 %10, %18, off offset:2048 sc0 sc1\n\t"
    "global_load_dwordx4 %11, %18, off offset:2560 sc0 sc1\n\t"
    "global_load_dwordx4 %12, %19, off sc0 sc1\n\t"
    "global_load_dwordx4 %13, %19, off offset:512 sc0 sc1\n\t"
    "global_load_dwordx4 %14, %19, off offset:2048 sc0 sc1\n\t"
    "global_load_dwordx4 %15, %19, off offset:2560 sc0 sc1\n\t"
    "s_waitcnt vmcnt(0)"
    : "=&v"(q0),"=&v"(q1),"=&v"(q2),"=&v"(q3),"=&v"(q4),"=&v"(q5),"=&v"(q6),"=&v"(q7),
      "=&v"(q8),"=&v"(q9),"=&v"(q10),"=&v"(q11),"=&v"(q12),"=&v"(q13),"=&v"(q14),"=&v"(q15)
    : "v"(b0), "v"(b1), "v"(b2), "v"(b3)
    : "memory");
  const unsigned S = 0xFFFFFFFFu;
  bool bad = false;
#define CK(q) bad |= (q[0]==S)|(q[1]==S)|(q[2]==S)|(q[3]==S)
  CK(q0);CK(q1);CK(q2);CK(q3);CK(q4);CK(q5);CK(q6);CK(q7);
  CK(q8);CK(q9);CK(q10);CK(q11);CK(q12);CK(q13);CK(q14);CK(q15);
#undef CK
  union U { u32x4 u; bf16x8 b; } cv;
  cv.u=q0;  afr0[0]=cv.b; cv.u=q1;  afr1[0]=cv.b; cv.u=q2;  afr0[1]=cv.b; cv.u=q3;  afr1[1]=cv.b;
  cv.u=q4;  afr0[2]=cv.b; cv.u=q5;  afr1[2]=cv.b; cv.u=q6;  afr0[3]=cv.b; cv.u=q7;  afr1[3]=cv.b;
  cv.u=q8;  afr0[4]=cv.b; cv.u=q9;  afr1[4]=cv.b; cv.u=q10; afr0[5]=cv.b; cv.u=q11; afr1[5]=cv.b;
  cv.u=q12; afr0[6]=cv.b; cv.u=q13; afr1[6]=cv.b; cv.u=q14; afr0[7]=cv.b; cv.u=q15; afr1[7]=cv.b;
  return !bad;
}

// ---------------- embedding gather + mask ----------------
__global__ void k_embed(const int* __restrict__ x, const float* __restrict__ tab,
                        unsigned short* __restrict__ emb, int* __restrict__ mask) {
  int t = blockIdx.x, b = blockIdx.y;
  int tok = x[b * S_LEN + t];
  if (threadIdx.x == 0) mask[t * NB + b] = (tok != 0);
  const float4* src = (const float4*)(tab + (size_t)tok * UDIM);
  ushort4* dst = (ushort4*)(emb + ((size_t)t * NB + b) * UDIM);
  int i = threadIdx.x;
  float4 v = src[i];
  ushort4 o;
  o.x = f2bf(v.x); o.y = f2bf(v.y); o.z = f2bf(v.z); o.w = f2bf(v.w);
  dst[i] = o;
}

// ---------------- weight transpose/convert ----------------
__global__ void k_wprep(WPtrs wp, unsigned short* __restrict__ wsW) {
  int bid = blockIdx.x;
  int kt = bid & 31; bid >>= 5;
  int g  = bid % 3;  bid /= 3;
  int wg = bid & 31; bid >>= 5;
  int slab = bid;                        // 0..7 : (chain, mat)
  const float* src = wp.p[slab];
  int tid = threadIdx.x;
  int r = tid >> 4, cc = tid & 15;
  __shared__ float ldsT[16][17];
  ldsT[cc][r] = src[(size_t)(kt * 16 + r) * 1536 + g * 512 + wg * 16 + cc];
  __syncthreads();
  size_t off = ((size_t)slab * WGS + wg) * (48 * 512) + (size_t)(g * 16 + r) * 512 + kt * 16 + cc;
  wsW[off] = f2bf(ldsT[r][cc]);
}

// ---------------- persistent recurrent kernel ----------------
// chains: 0=fw_l0 1=fw_l1 2=bw_l0 3=bw_l1. 32 WGs/chain, each owns 16 h-cols.
// waves: 0:(x@k,Klo) 1:(h@rk,Klo) 2:(x@k,Khi) 3:(h@rk,Khi)
// R16 = R12 (no flags, unit-slab hist, hint-first) with the hint poll
// PIPELINED at depth 3 (poll period ~RT/3 instead of RT).
__global__ __launch_bounds__(256, 1) void k_rnn(
    const unsigned short* __restrict__ wsW, const unsigned short* __restrict__ emb,
    unsigned short* __restrict__ hist, const int* __restrict__ mask,
    const float* __restrict__ state, BPtrs bp, float* __restrict__ out) {
  __shared__ short sW[2 * 48 * 512];        // 98304 B, XOR-swizzled rows
  __shared__ float sAcc[2][2][2][32][48];   // [parity][khalf][mat]
  __shared__ float sBias[2][48];
  __shared__ unsigned char sMask[S_LEN][NB];

  int tid = threadIdx.x;
  int bid = blockIdx.x;
  int xcd = bid & 7;                      // perf heuristic only
  int c = xcd >> 1;                       // chain
  int w = ((bid >> 3) << 1) | (xcd & 1);  // wg-in-chain 0..31
  int layer = c & 1;
  bool back = (c >= 2);
  int lane = tid & 63;
  int wave = tid >> 6;
  int mat = wave & 1;                     // 0: x@k, 1: h@rk
  int kh = wave >> 1;                     // K-half

  // combine-phase ownership: thread -> (b, j0, j0+1); h and prev in registers
  int cb = tid >> 3;
  int cj = (tid & 7) << 1;
  float hreg0, hreg1, preg0 = 0.f, preg1 = 0.f;

  char* histc = (char*)hist;

  // ---- init: weights -> LDS (swizzled), biases, mask, state ----
  {
    const size_t slabSz = 48 * 512;
    for (int ch = tid; ch < 2 * 48 * 64; ch += 256) {
      int m = ch / (48 * 64);
      int rem = ch % (48 * 64);
      int nl = rem >> 6;
      int k16 = rem & 63;
      const unsigned short* sp =
          wsW + ((size_t)((c * 2 + m) * WGS) + w) * slabSz + (size_t)nl * 512 + k16 * 8;
      bf16x8 val = *(const bf16x8*)sp;
      int byte = m * 49152 + nl * 1024 + ((k16 * 16) ^ ((nl & 7) << 4));
      *(bf16x8*)((char*)sW + byte) = val;
    }
    const float* bptr = bp.p[c];
    for (int i = tid; i < 96; i += 256) {
      int m = i / 48, nl = i % 48;
      int col = (nl / 16) * 512 + w * 16 + (nl & 15);
      sBias[m][nl] = bptr[m * 1536 + col];
    }
    for (int i = tid; i < S_LEN * NB; i += 256)
      sMask[i >> 5][i & 31] = (unsigned char)(mask[i] != 0);
    // state -> h registers + publish hist slot 0 (contiguous unit slab)
    int col = w * 16 + cj;
    hreg0 = state[((size_t)c * NB + cb) * UDIM + col];
    hreg1 = state[((size_t)c * NB + cb) * UDIM + col + 1];
    unsigned pk = (unsigned)f2bf(hreg0) | ((unsigned)f2bf(hreg1) << 16);
    st_u32c(histc + SLAB(c, 0) + ((size_t)w << 10) + cb * 32 + cj * 2, pk);
  }
  __syncthreads();   // implicit drain commits slot-0 publish (once, off-loop)

  int r15 = lane & 15, quad = lane >> 4;
  // unit-slab lane base for the 16-batch
  int lbase = ((kh * 16 + (quad >> 1)) << 10) + ((quad & 1) << 4) + r15 * 32;
  // hint sample: lane -> slab (kh*16 + (lane&15)), line (lane>>4)*2+1, last u32
  int hoff = ((kh * 16 + (lane & 15)) << 10) + ((((lane >> 4) << 1) + 1) << 7) + 124;
  bool ownHint = (kh * 16 + (lane & 15)) == w;   // own slab: self-produced
  const char* dummyHp = (const char*)mask;        // values 0/1: never sentinel
  // emb lane base (row-major layout)
  int abase = r15 * UDIM + kh * 256 + quad * 8;
  int matbase = mat * 49152;

  for (int t = 0; t < S_LEN; ++t) {
    int par = t & 1;
    int treal = back ? (S_LEN - 1 - t) : t;

    bf16x8 afr0[8], afr1[8];
    if (mat == 0 && layer == 0) {
      // layer0 x: plain cached reads of emb
      const short* a16 = (const short*)(emb + (size_t)treal * NB * UDIM);
#pragma unroll
      for (int kc = 0; kc < 8; ++kc) {
        afr0[kc] = *(const bf16x8*)(a16 + abase + kc * 32);
        afr1[kc] = *(const bf16x8*)(a16 + abase + 16 * UDIM + kc * 32);
      }
    } else {
      // h (mat1) or layer1-x: pipelined hint poll, then batch + validate
      const char* sb;
      bool skipOwn;
      if (mat == 0) { sb = histc + SLAB(c - 1, t + 1); skipOwn = false; }
      else          { sb = histc + SLAB(c, t);          skipOwn = true; }
      bool own = skipOwn && ownHint;
      const char* hp = own ? dummyHp : (sb + hoff);
      poll3(hp);
      const char* b0p = sb + lbase;
      bool ok = ld_slab16(b0p, b0p + 4096, b0p + 8192, b0p + 12288, afr0, afr1);
      while (!__all(ok))
        ok = ld_slab16(b0p, b0p + 4096, b0p + 8192, b0p + 12288, afr0, afr1);
    }

    // GEMM: (32 x 48) += A(32 x 256-half) * W(256-half x 48)
    f32x4 acc[2][3];
#pragma unroll
    for (int a = 0; a < 2; a++)
#pragma unroll
      for (int g = 0; g < 3; g++) acc[a][g] = (f32x4){0.f, 0.f, 0.f, 0.f};
#pragma unroll
    for (int kc = 0; kc < 8; ++kc) {
#pragma unroll
      for (int g = 0; g < 3; ++g) {
        int nl = g * 16 + r15;
        int koff = kh * 512 + kc * 64 + quad * 16;
        int byte = matbase + nl * 1024 + (koff ^ ((nl & 7) << 4));
        bf16x8 bw = *(const bf16x8*)((const char*)sW + byte);
        acc[0][g] = __builtin_amdgcn_mfma_f32_16x16x32_bf16(afr0[kc], bw, acc[0][g], 0, 0, 0);
        acc[1][g] = __builtin_amdgcn_mfma_f32_16x16x32_bf16(afr1[kc], bw, acc[1][g], 0, 0, 0);
      }
    }
#pragma unroll
    for (int mt = 0; mt < 2; ++mt)
#pragma unroll
      for (int g = 0; g < 3; ++g)
#pragma unroll
        for (int rr = 0; rr < 4; ++rr)
          sAcc[par][kh][mat][mt * 16 + quad * 4 + rr][g * 16 + r15] = acc[mt][g][rr];
    __syncthreads();   // the ONLY barrier per step (sAcc parity-buffered)

    // combine + GRU nonlinearity: this thread owns (cb, cj) and (cb, cj+1)
    float hn0, hn1;
    bool mk;
    {
      int b = cb, j0 = cj;
      mk = sMask[treal][b] != 0;
#pragma unroll
      for (int u = 0; u < 2; ++u) {
        int j = j0 + u;
        float az = sAcc[par][0][0][b][j]      + sAcc[par][1][0][b][j]      + sBias[0][j];
        float ar = sAcc[par][0][0][b][16 + j] + sAcc[par][1][0][b][16 + j] + sBias[0][16 + j];
        float ah = sAcc[par][0][0][b][32 + j] + sAcc[par][1][0][b][32 + j] + sBias[0][32 + j];
        float iz = sAcc[par][0][1][b][j]      + sAcc[par][1][1][b][j]      + sBias[1][j];
        float ir = sAcc[par][0][1][b][16 + j] + sAcc[par][1][1][b][16 + j] + sBias[1][16 + j];
        float ih = sAcc[par][0][1][b][32 + j] + sAcc[par][1][1][b][32 + j] + sBias[1][32 + j];
        float z = 1.f / (1.f + __expf(-(az + iz)));
        float r = 1.f / (1.f + __expf(-(ar + ir)));
        float pre = ah + r * ih;
        pre = fminf(fmaxf(pre, -30.f), 30.f);
        float e2 = __expf(2.f * pre);
        float hh = (e2 - 1.f) / (e2 + 1.f);
        float hold = (u == 0) ? hreg0 : hreg1;
        float hv = z * hold + (1.f - z) * hh;
        hv = mk ? hv : hold;
        if (u == 0) hn0 = hv; else hn1 = hv;
      }
      hreg0 = hn0; hreg1 = hn1;
      // publish h(t+1) into OUR contiguous slab: fire-and-forget, no drain
      unsigned pk = (unsigned)f2bf(hn0) | ((unsigned)f2bf(hn1) << 16);
      st_u32c(histc + SLAB(c, t + 1) + ((size_t)w << 10) + cb * 32 + cj * 2, pk);
    }

    // out-writes (off the publish path)
    if (layer == 1) {
      float o0 = mk ? hn0 : preg0;
      float o1 = mk ? hn1 : preg1;
      preg0 = o0; preg1 = o1;
      *(float2*)(out + ((size_t)cb * S_LEN + treal) * 1024 + (back ? 512 : 0) + w * 16 + cj) =
          make_float2(o0, o1);
    }
    if (t == S_LEN - 1) {
      *(float2*)(out + (size_t)NB * S_LEN * 1024 + ((size_t)c * NB + cb) * UDIM + w * 16 + cj) =
          make_float2(hn0, hn1);
    }
  }
}

extern "C" void kernel_launch(void* const* d_in, const int* in_sizes, int n_in,
                              void* d_out, int out_size, void* d_ws, size_t ws_size,
                              hipStream_t stream) {
  const int* x = (const int*)d_in[0];
  const float* state = (const float*)d_in[1];
  const float* tab = (const float*)d_in[2];
  WPtrs wp;
  wp.p[0] = (const float*)d_in[3];   // fk0
  wp.p[1] = (const float*)d_in[4];   // frk0
  wp.p[2] = (const float*)d_in[6];   // fk1
  wp.p[3] = (const float*)d_in[7];   // frk1
  wp.p[4] = (const float*)d_in[9];   // bk0
  wp.p[5] = (const float*)d_in[10];  // brk0
  wp.p[6] = (const float*)d_in[12];  // bk1
  wp.p[7] = (const float*)d_in[13];  // brk1
  BPtrs bp;
  bp.p[0] = (const float*)d_in[5];   // fb0
  bp.p[1] = (const float*)d_in[8];   // fb1
  bp.p[2] = (const float*)d_in[11];  // bb0
  bp.p[3] = (const float*)d_in[14];  // bb1
  float* out = (float*)d_out;

  char* ws = (char*)d_ws;
  size_t off = 0;
  unsigned short* wsW = (unsigned short*)(ws + off); off += (size_t)8 * 32 * 48 * 512 * 2;   // 25.2 MB
  unsigned short* embp = (unsigned short*)(ws + off); off += (size_t)S_LEN * NB * UDIM * 2;  // 8.4 MB
  unsigned short* hist = (unsigned short*)(ws + off);
  size_t histBytes = (size_t)4 * 257 * 32 * 1024;      off += histBytes;                     // 33.7 MB
  int* maskp = (int*)(ws + off); off += (size_t)S_LEN * NB * 4;

  hipMemsetAsync(hist, 0xFF, histBytes, stream);   // sentinel-poison write-once h
  k_embed<<<dim3(S_LEN, NB), 128, 0, stream>>>(x, tab, embp, maskp);
  k_wprep<<<8 * 32 * 3 * 32, 256, 0, stream>>>(wp, wsW);
  k_rnn<<<128, 256, 0, stream>>>(wsW, embp, hist, maskp, state, bp, out);
}

// Round 17
// 977.062 us; speedup vs baseline: 1.0498x; 1.0498x over previous
//
#include <hip/hip_runtime.h>
#include <hip/hip_bf16.h>

#define S_LEN 256
#define NB 32
#define UDIM 512
#define WGS 32    // workgroups per chain

typedef __attribute__((ext_vector_type(8))) short bf16x8;
typedef __attribute__((ext_vector_type(4))) float f32x4;
typedef __attribute__((ext_vector_type(4))) unsigned u32x4;

struct WPtrs { const float* p[8]; };
struct BPtrs { const float* p[4]; };

// hist layout: [c][slot][unit][b][j]  -- each unit owns a CONTIGUOUS 1KB slab
// (8 exclusive 128B lines per producer per step; no cross-CU line sharing).
#define SLAB(c, slot) ((((size_t)(c) * 257 + (slot)) * 32) << 10)

__device__ __forceinline__ unsigned short f2bf(float f) {
  union { float f; unsigned u; } v; v.f = f;
  unsigned r = v.u + 0x7fffu + ((v.u >> 16) & 1u);
  return (unsigned short)(r >> 16);
}

// ---- coherent (cross-XCD) memory ops ----
__device__ __forceinline__ unsigned ld_word_coh(const char* p) {
  unsigned v;
  asm volatile("global_load_dword %0, %1, off sc0 sc1\n\ts_waitcnt vmcnt(0)"
               : "=&v"(v) : "v"(p) : "memory");
  return v;
}
__device__ __forceinline__ void st_u32c(void* p, unsigned v) {
  asm volatile("global_store_dword %0, %1, off sc0 sc1" :: "v"(p), "v"(v) : "memory");
}

// Coherent 16-load batch over the unit-slab layout. 4 base pointers (b0..b3 =
// lane base + m*4096) x 4 imm offsets {0,512,2048,2560}. vmcnt(0) INSIDE the
// asm; returns per-lane "no 0xFFFFFFFF sentinel word" (commit validation).
__device__ __forceinline__ bool ld_slab16(const char* b0, const char* b1,
                                          const char* b2, const char* b3,
                                          bf16x8* afr0, bf16x8* afr1) {
  u32x4 q0,q1,q2,q3,q4,q5,q6,q7,q8,q9,q10,q11,q12,q13,q14,q15;
  asm volatile(
    "global_load_dwordx4 %0, %16, off sc0 sc1\n\t"
    "global_load_dwordx4 %1, %16, off offset:512 sc0 sc1\n\t"
    "global_load_dwordx4 %2, %16, off offset:2048 sc0 sc1\n\t"
    "global_load_dwordx4 %3, %16, off offset:2560 sc0 sc1\n\t"
    "global_load_dwordx4 %4, %17, off sc0 sc1\n\t"
    "global_load_dwordx4 %5, %17, off offset:512 sc0 sc1\n\t"
    "global_load_dwordx4 %6, %17, off offset:2048 sc0 sc1\n\t"
    "global_load_dwordx4 %7, %17, off offset:2560 sc0 sc1\n\t"
    "global_load_dwordx4 %8, %18, off sc0 sc1\n\t"
    "global_load_dwordx4 %9, %18, off offset:512 sc0 sc1\n\t"
    "global_load_dwordx4 %10, %18, off offset:2048 sc0 sc1\n\t"
    "global_load_dwordx4 %11, %18, off offset:2560 sc0 sc1\n\t"
    "global_load_dwordx4 %12, %19, off sc0 sc1\n\t"
    "global_load_dwordx4 %13, %19, off offset:512 sc0 sc1\n\t"
    "global_load_dwordx4 %14, %19, off offset:2048 sc0 sc1\n\t"
    "global_load_dwordx4 %15, %19, off offset:2560 sc0 sc1\n\t"
    "s_waitcnt vmcnt(0)"
    : "=&v"(q0),"=&v"(q1),"=&v"(q2),"=&v"(q3),"=&v"(q4),"=&v"(q5),"=&v"(q6),"=&v"(q7),
      "=&v"(q8),"=&v"(q9),"=&v"(q10),"=&v"(q11),"=&v"(q12),"=&v"(q13),"=&v"(q14),"=&v"(q15)
    : "v"(b0), "v"(b1), "v"(b2), "v"(b3)
    : "memory");
  const unsigned S = 0xFFFFFFFFu;
  bool bad = false;
#define CK(q) bad |= (q[0]==S)|(q[1]==S)|(q[2]==S)|(q[3]==S)
  CK(q0);CK(q1);CK(q2);CK(q3);CK(q4);CK(q5);CK(q6);CK(q7);
  CK(q8);CK(q9);CK(q10);CK(q11);CK(q12);CK(q13);CK(q14);CK(q15);
#undef CK
  union U { u32x4 u; bf16x8 b; } cv;
  cv.u=q0;  afr0[0]=cv.b; cv.u=q1;  afr1[0]=cv.b; cv.u=q2;  afr0[1]=cv.b; cv.u=q3;  afr1[1]=cv.b;
  cv.u=q4;  afr0[2]=cv.b; cv.u=q5;  afr1[2]=cv.b; cv.u=q6;  afr0[3]=cv.b; cv.u=q7;  afr1[3]=cv.b;
  cv.u=q8;  afr0[4]=cv.b; cv.u=q9;  afr1[4]=cv.b; cv.u=q10; afr0[5]=cv.b; cv.u=q11; afr1[5]=cv.b;
  cv.u=q12; afr0[6]=cv.b; cv.u=q13; afr1[6]=cv.b; cv.u=q14; afr0[7]=cv.b; cv.u=q15; afr1[7]=cv.b;
  return !bad;
}

// ---------------- embedding gather + mask ----------------
__global__ void k_embed(const int* __restrict__ x, const float* __restrict__ tab,
                        unsigned short* __restrict__ emb, int* __restrict__ mask) {
  int t = blockIdx.x, b = blockIdx.y;
  int tok = x[b * S_LEN + t];
  if (threadIdx.x == 0) mask[t * NB + b] = (tok != 0);
  const float4* src = (const float4*)(tab + (size_t)tok * UDIM);
  ushort4* dst = (ushort4*)(emb + ((size_t)t * NB + b) * UDIM);
  int i = threadIdx.x;                   // 128 threads * 4 floats = 512
  float4 v = src[i];
  ushort4 o;
  o.x = f2bf(v.x); o.y = f2bf(v.y); o.z = f2bf(v.z); o.w = f2bf(v.w);
  dst[i] = o;
}

// ---------------- weight transpose/convert ----------------
__global__ void k_wprep(WPtrs wp, unsigned short* __restrict__ wsW) {
  int bid = blockIdx.x;
  int kt = bid & 31; bid >>= 5;
  int g  = bid % 3;  bid /= 3;
  int wg = bid & 31; bid >>= 5;
  int slab = bid;                        // 0..7 : (chain, mat)
  const float* src = wp.p[slab];
  int tid = threadIdx.x;
  int r = tid >> 4, cc = tid & 15;
  __shared__ float ldsT[16][17];
  ldsT[cc][r] = src[(size_t)(kt * 16 + r) * 1536 + g * 512 + wg * 16 + cc];
  __syncthreads();
  size_t off = ((size_t)slab * WGS + wg) * (48 * 512) + (size_t)(g * 16 + r) * 512 + kt * 16 + cc;
  wsW[off] = f2bf(ldsT[r][cc]);
}

// ---------------- persistent recurrent kernel ----------------
// chains: 0=fw_l0 1=fw_l1 2=bw_l0 3=bw_l1. 32 WGs/chain, each owns 16 h-cols.
// waves: 0:(x@k,Klo) 1:(h@rk,Klo) 2:(x@k,Khi) 3:(h@rk,Khi)
// Protocol (best-of-session, R12): NO flags. hist slabs are 0xFF-poisoned,
// write-once. Consumer wave hint-polls ONE word per needed slab (64 lanes =
// 16 slabs x 4 sample lines, one instruction/poll), then batch-reads +
// sentinel-validates (rare whole-batch retry). One barrier per step (sAcc
// parity covers wave skew). Producers publish fire-and-forget into exclusive
// full 128B lines (unit-contiguous slabs).
__global__ __launch_bounds__(256, 1) void k_rnn(
    const unsigned short* __restrict__ wsW, const unsigned short* __restrict__ emb,
    unsigned short* __restrict__ hist, const int* __restrict__ mask,
    const float* __restrict__ state, BPtrs bp, float* __restrict__ out) {
  __shared__ short sW[2 * 48 * 512];        // 98304 B, XOR-swizzled rows
  __shared__ float sAcc[2][2][2][32][48];   // [parity][khalf][mat]
  __shared__ float sBias[2][48];
  __shared__ unsigned char sMask[S_LEN][NB];

  int tid = threadIdx.x;
  int bid = blockIdx.x;
  int xcd = bid & 7;                      // perf heuristic only
  int c = xcd >> 1;                       // chain
  int w = ((bid >> 3) << 1) | (xcd & 1);  // wg-in-chain 0..31
  int layer = c & 1;
  bool back = (c >= 2);
  int lane = tid & 63;
  int wave = tid >> 6;
  int mat = wave & 1;                     // 0: x@k, 1: h@rk
  int kh = wave >> 1;                     // K-half

  // combine-phase ownership: thread -> (b, j0, j0+1); h and prev in registers
  int cb = tid >> 3;
  int cj = (tid & 7) << 1;
  float hreg0, hreg1, preg0 = 0.f, preg1 = 0.f;

  char* histc = (char*)hist;

  // ---- init: weights -> LDS (swizzled), biases, mask, state ----
  {
    const size_t slabSz = 48 * 512;
    for (int ch = tid; ch < 2 * 48 * 64; ch += 256) {
      int m = ch / (48 * 64);
      int rem = ch % (48 * 64);
      int nl = rem >> 6;
      int k16 = rem & 63;
      const unsigned short* sp =
          wsW + ((size_t)((c * 2 + m) * WGS) + w) * slabSz + (size_t)nl * 512 + k16 * 8;
      bf16x8 val = *(const bf16x8*)sp;
      int byte = m * 49152 + nl * 1024 + ((k16 * 16) ^ ((nl & 7) << 4));
      *(bf16x8*)((char*)sW + byte) = val;
    }
    const float* bptr = bp.p[c];
    for (int i = tid; i < 96; i += 256) {
      int m = i / 48, nl = i % 48;
      int col = (nl / 16) * 512 + w * 16 + (nl & 15);
      sBias[m][nl] = bptr[m * 1536 + col];
    }
    for (int i = tid; i < S_LEN * NB; i += 256)
      sMask[i >> 5][i & 31] = (unsigned char)(mask[i] != 0);
    // state -> h registers + publish hist slot 0 (contiguous unit slab)
    int col = w * 16 + cj;
    hreg0 = state[((size_t)c * NB + cb) * UDIM + col];
    hreg1 = state[((size_t)c * NB + cb) * UDIM + col + 1];
    unsigned pk = (unsigned)f2bf(hreg0) | ((unsigned)f2bf(hreg1) << 16);
    st_u32c(histc + SLAB(c, 0) + ((size_t)w << 10) + cb * 32 + cj * 2, pk);
  }
  __syncthreads();   // implicit drain commits slot-0 publish (once, off-loop)

  int r15 = lane & 15, quad = lane >> 4;
  // unit-slab lane base: u = kh*16 + 4m + (quad>>1) (m = base idx); j from quad&1
  int lbase = ((kh * 16 + (quad >> 1)) << 10) + ((quad & 1) << 4) + r15 * 32;
  // hint sample: lane -> slab (kh*16 + (lane&15)), line (lane>>4)*2+1, last u32
  int hoff = ((kh * 16 + (lane & 15)) << 10) + ((((lane >> 4) << 1) + 1) << 7) + 124;
  bool ownHint = (kh * 16 + (lane & 15)) == w;   // own slab: self-produced
  // emb lane base (row-major layout)
  int abase = r15 * UDIM + kh * 256 + quad * 8;
  int matbase = mat * 49152;

  for (int t = 0; t < S_LEN; ++t) {
    int par = t & 1;
    int treal = back ? (S_LEN - 1 - t) : t;

    bf16x8 afr0[8], afr1[8];
    if (mat == 0 && layer == 0) {
      // layer0 x: plain cached reads of emb
      const short* a16 = (const short*)(emb + (size_t)treal * NB * UDIM);
#pragma unroll
      for (int kc = 0; kc < 8; ++kc) {
        afr0[kc] = *(const bf16x8*)(a16 + abase + kc * 32);
        afr1[kc] = *(const bf16x8*)(a16 + abase + 16 * UDIM + kc * 32);
      }
    } else {
      // h (mat1) or layer1-x: hint-poll the 16 needed slabs, then batch+validate
      const char* sb;
      bool skipOwn;
      if (mat == 0) { sb = histc + SLAB(c - 1, t + 1); skipOwn = false; }
      else          { sb = histc + SLAB(c, t);          skipOwn = true; }
      const char* hp = sb + hoff;
      bool own = skipOwn && ownHint;
      unsigned hv = own ? 0u : ld_word_coh(hp);
      while (!__all(own || hv != 0xFFFFFFFFu))
        hv = own ? 0u : ld_word_coh(hp);
      const char* b0 = sb + lbase;
      bool ok = ld_slab16(b0, b0 + 4096, b0 + 8192, b0 + 12288, afr0, afr1);
      while (!__all(ok))
        ok = ld_slab16(b0, b0 + 4096, b0 + 8192, b0 + 12288, afr0, afr1);
    }

    // GEMM: (32 x 48) += A(32 x 256-half) * W(256-half x 48)
    f32x4 acc[2][3];
#pragma unroll
    for (int a = 0; a < 2; a++)
#pragma unroll
      for (int g = 0; g < 3; g++) acc[a][g] = (f32x4){0.f, 0.f, 0.f, 0.f};
#pragma unroll
    for (int kc = 0; kc < 8; ++kc) {
#pragma unroll
      for (int g = 0; g < 3; ++g) {
        int nl = g * 16 + r15;
        int koff = kh * 512 + kc * 64 + quad * 16;
        int byte = matbase + nl * 1024 + (koff ^ ((nl & 7) << 4));
        bf16x8 bw = *(const bf16x8*)((const char*)sW + byte);
        acc[0][g] = __builtin_amdgcn_mfma_f32_16x16x32_bf16(afr0[kc], bw, acc[0][g], 0, 0, 0);
        acc[1][g] = __builtin_amdgcn_mfma_f32_16x16x32_bf16(afr1[kc], bw, acc[1][g], 0, 0, 0);
      }
    }
#pragma unroll
    for (int mt = 0; mt < 2; ++mt)
#pragma unroll
      for (int g = 0; g < 3; ++g)
#pragma unroll
        for (int rr = 0; rr < 4; ++rr)
          sAcc[par][kh][mat][mt * 16 + quad * 4 + rr][g * 16 + r15] = acc[mt][g][rr];
    __syncthreads();   // the ONLY barrier per step (sAcc parity-buffered)

    // combine + GRU nonlinearity: this thread owns (cb, cj) and (cb, cj+1)
    float hn0, hn1;
    bool mk;
    {
      int b = cb, j0 = cj;
      mk = sMask[treal][b] != 0;
#pragma unroll
      for (int u = 0; u < 2; ++u) {
        int j = j0 + u;
        float az = sAcc[par][0][0][b][j]      + sAcc[par][1][0][b][j]      + sBias[0][j];
        float ar = sAcc[par][0][0][b][16 + j] + sAcc[par][1][0][b][16 + j] + sBias[0][16 + j];
        float ah = sAcc[par][0][0][b][32 + j] + sAcc[par][1][0][b][32 + j] + sBias[0][32 + j];
        float iz = sAcc[par][0][1][b][j]      + sAcc[par][1][1][b][j]      + sBias[1][j];
        float ir = sAcc[par][0][1][b][16 + j] + sAcc[par][1][1][b][16 + j] + sBias[1][16 + j];
        float ih = sAcc[par][0][1][b][32 + j] + sAcc[par][1][1][b][32 + j] + sBias[1][32 + j];
        float z = 1.f / (1.f + __expf(-(az + iz)));
        float r = 1.f / (1.f + __expf(-(ar + ir)));
        float pre = ah + r * ih;
        pre = fminf(fmaxf(pre, -30.f), 30.f);
        float e2 = __expf(2.f * pre);
        float hh = (e2 - 1.f) / (e2 + 1.f);
        float hold = (u == 0) ? hreg0 : hreg1;
        float hv = z * hold + (1.f - z) * hh;
        hv = mk ? hv : hold;
        if (u == 0) hn0 = hv; else hn1 = hv;
      }
      hreg0 = hn0; hreg1 = hn1;
      // publish h(t+1) into OUR contiguous slab: fire-and-forget, no drain,
      // no flag -- consumers hint-poll the data itself.
      unsigned pk = (unsigned)f2bf(hn0) | ((unsigned)f2bf(hn1) << 16);
      st_u32c(histc + SLAB(c, t + 1) + ((size_t)w << 10) + cb * 32 + cj * 2, pk);
    }

    // out-writes (off the publish path)
    if (layer == 1) {
      float o0 = mk ? hn0 : preg0;
      float o1 = mk ? hn1 : preg1;
      preg0 = o0; preg1 = o1;
      *(float2*)(out + ((size_t)cb * S_LEN + treal) * 1024 + (back ? 512 : 0) + w * 16 + cj) =
          make_float2(o0, o1);
    }
    if (t == S_LEN - 1) {
      *(float2*)(out + (size_t)NB * S_LEN * 1024 + ((size_t)c * NB + cb) * UDIM + w * 16 + cj) =
          make_float2(hn0, hn1);
    }
  }
}

extern "C" void kernel_launch(void* const* d_in, const int* in_sizes, int n_in,
                              void* d_out, int out_size, void* d_ws, size_t ws_size,
                              hipStream_t stream) {
  const int* x = (const int*)d_in[0];
  const float* state = (const float*)d_in[1];
  const float* tab = (const float*)d_in[2];
  WPtrs wp;
  wp.p[0] = (const float*)d_in[3];   // fk0
  wp.p[1] = (const float*)d_in[4];   // frk0
  wp.p[2] = (const float*)d_in[6];   // fk1
  wp.p[3] = (const float*)d_in[7];   // frk1
  wp.p[4] = (const float*)d_in[9];   // bk0
  wp.p[5] = (const float*)d_in[10];  // brk0
  wp.p[6] = (const float*)d_in[12];  // bk1
  wp.p[7] = (const float*)d_in[13];  // brk1
  BPtrs bp;
  bp.p[0] = (const float*)d_in[5];   // fb0
  bp.p[1] = (const float*)d_in[8];   // fb1
  bp.p[2] = (const float*)d_in[11];  // bb0
  bp.p[3] = (const float*)d_in[14];  // bb1
  float* out = (float*)d_out;

  char* ws = (char*)d_ws;
  size_t off = 0;
  unsigned short* wsW = (unsigned short*)(ws + off); off += (size_t)8 * 32 * 48 * 512 * 2;   // 25.2 MB
  unsigned short* embp = (unsigned short*)(ws + off); off += (size_t)S_LEN * NB * UDIM * 2;  // 8.4 MB
  unsigned short* hist = (unsigned short*)(ws + off);
  size_t histBytes = (size_t)4 * 257 * 32 * 1024;      off += histBytes;                     // 33.7 MB
  int* maskp = (int*)(ws + off); off += (size_t)S_LEN * NB * 4;

  hipMemsetAsync(hist, 0xFF, histBytes, stream);   // sentinel-poison write-once h
  k_embed<<<dim3(S_LEN, NB), 128, 0, stream>>>(x, tab, embp, maskp);
  k_wprep<<<8 * 32 * 3 * 32, 256, 0, stream>>>(wp, wsW);
  k_rnn<<<128, 256, 0, stream>>>(wsW, embp, hist, maskp, state, bp, out);
}